// Round 1
// baseline (463.266 us; speedup 1.0000x reference)
//
#include <hip/hip_runtime.h>
#include <math.h>

// Problem constants (match reference)
#define NROWS   8192
#define DDIM    1024
#define NSTEPS  50
#define EPL     16          // elements per lane: 1024 / 64
#define WAVES_PER_BLOCK 4   // 256 threads

// Adam hyperparams
#define LR   0.01f
#define B1   0.9f
#define B2   0.999f
#define EPSA 1e-8f

__global__ __launch_bounds__(256) void adam_rows_kernel(
    const float* __restrict__ s,       // [NROWS, DDIM]
    const float* __restrict__ tconf,   // [NROWS, 1]
    const float* __restrict__ W,       // [1, DDIM]
    const float* __restrict__ bias,    // [1]
    float* __restrict__ out)           // [NROWS, DDIM]
{
    const int lane = threadIdx.x & 63;
    const int wave = threadIdx.x >> 6;
    const int row  = blockIdx.x * WAVES_PER_BLOCK + wave;

    const float bb = bias[0];
    const float tc = tconf[row];

    // Element mapping: d = c*256 + lane*4 + j   (c in 0..3, j in 0..3)
    // -> coalesced float4 loads: lane l reads 16B at chunk base + l*16.
    float w[EPL], s0[EPL], sp[EPL], m[EPL], v[EPL];

    const float4* W4 = reinterpret_cast<const float4*>(W);
    const float4* S4 = reinterpret_cast<const float4*>(s + (size_t)row * DDIM);

    #pragma unroll
    for (int c = 0; c < 4; ++c) {
        float4 wv = W4[c * 64 + lane];
        float4 sv = S4[c * 64 + lane];
        w[c*4+0] = wv.x; w[c*4+1] = wv.y; w[c*4+2] = wv.z; w[c*4+3] = wv.w;
        s0[c*4+0] = sv.x; s0[c*4+1] = sv.y; s0[c*4+2] = sv.z; s0[c*4+3] = sv.w;
    }

    #pragma unroll
    for (int i = 0; i < EPL; ++i) { sp[i] = s0[i]; m[i] = 0.0f; v[i] = 0.0f; }

    const float inv_nl1   = 1.0f / ((float)NROWS * (float)DDIM);  // 1/(B*D)
    const float two_over_b = 2.0f / (float)NROWS;

    float b1p = 1.0f, b2p = 1.0f;

    for (int step = 0; step < NSTEPS; ++step) {
        b1p *= B1;
        b2p *= B2;

        // z = sp . W  (wave-wide reduction) + b
        float dot = 0.0f;
        #pragma unroll
        for (int i = 0; i < EPL; ++i) dot = fmaf(sp[i], w[i], dot);
        #pragma unroll
        for (int off = 32; off >= 1; off >>= 1) dot += __shfl_xor(dot, off, 64);

        const float z  = dot + bb;
        const float p  = 1.0f / (1.0f + expf(-z));
        const float gz = two_over_b * (p - tc) * (p * (1.0f - p));

        const float ib1 = 1.0f / (1.0f - b1p);
        const float ib2 = 1.0f / (1.0f - b2p);

        #pragma unroll
        for (int i = 0; i < EPL; ++i) {
            const float diff = sp[i] - s0[i];
            // sign(0) = 0, matching torch/jax sign semantics
            const float sg = (float)((diff > 0.0f) - (diff < 0.0f));
            const float g  = fmaf(gz, w[i], sg * inv_nl1);

            m[i] = fmaf(B1, m[i], (1.0f - B1) * g);
            v[i] = fmaf(B2, v[i], (1.0f - B2) * (g * g));

            const float mh  = m[i] * ib1;
            const float vh  = v[i] * ib2;
            const float den = sqrtf(vh) + EPSA;
            sp[i] -= LR * mh / den;
        }
    }

    float4* O4 = reinterpret_cast<float4*>(out + (size_t)row * DDIM);
    #pragma unroll
    for (int c = 0; c < 4; ++c) {
        float4 ov;
        ov.x = sp[c*4+0]; ov.y = sp[c*4+1]; ov.z = sp[c*4+2]; ov.w = sp[c*4+3];
        O4[c * 64 + lane] = ov;
    }
}

extern "C" void kernel_launch(void* const* d_in, const int* in_sizes, int n_in,
                              void* d_out, int out_size, void* d_ws, size_t ws_size,
                              hipStream_t stream) {
    const float* s     = (const float*)d_in[0];
    const float* tconf = (const float*)d_in[1];
    const float* W     = (const float*)d_in[2];
    const float* bias  = (const float*)d_in[3];
    float* out = (float*)d_out;

    dim3 grid(NROWS / WAVES_PER_BLOCK);  // 2048 blocks
    dim3 block(64 * WAVES_PER_BLOCK);    // 256 threads
    adam_rows_kernel<<<grid, block, 0, stream>>>(s, tconf, W, bias, out);
}

// Round 2
// 195.507 us; speedup vs baseline: 2.3696x; 2.3696x over previous
//
#include <hip/hip_runtime.h>
#include <math.h>

// Problem constants (match reference)
#define NROWS   8192
#define DDIM    1024
#define NSTEPS  50
#define EPL     16          // elements per lane: 1024 / 64
#define WAVES_PER_BLOCK 4   // 256 threads

// Adam hyperparams
#define LR   0.01f
#define B1   0.9f
#define B2   0.999f
#define OMB1 0.1f           // 1 - B1
#define OMB2 0.001f         // 1 - B2
#define EPSA 1e-8f

__global__ __launch_bounds__(256) void adam_rows_kernel(
    const float* __restrict__ s,       // [NROWS, DDIM]
    const float* __restrict__ tconf,   // [NROWS, 1]
    const float* __restrict__ W,       // [1, DDIM]
    const float* __restrict__ bias,    // [1]
    float* __restrict__ out)           // [NROWS, DDIM]
{
    const int lane = threadIdx.x & 63;
    const int wave = threadIdx.x >> 6;
    const int row  = blockIdx.x * WAVES_PER_BLOCK + wave;

    const float bb = bias[0];
    const float tc = tconf[row];

    float w[EPL], s0[EPL], sp[EPL], m[EPL], v[EPL];

    const float4* W4 = reinterpret_cast<const float4*>(W);
    const float4* S4 = reinterpret_cast<const float4*>(s + (size_t)row * DDIM);

    #pragma unroll
    for (int c = 0; c < 4; ++c) {
        float4 wv = W4[c * 64 + lane];
        float4 sv = S4[c * 64 + lane];
        w[c*4+0] = wv.x; w[c*4+1] = wv.y; w[c*4+2] = wv.z; w[c*4+3] = wv.w;
        s0[c*4+0] = sv.x; s0[c*4+1] = sv.y; s0[c*4+2] = sv.z; s0[c*4+3] = sv.w;
    }

    #pragma unroll
    for (int i = 0; i < EPL; ++i) { sp[i] = s0[i]; m[i] = 0.0f; v[i] = 0.0f; }

    const float inv_nl1    = 1.0f / ((float)NROWS * (float)DDIM);  // 1/(B*D)
    const float two_over_b = 2.0f / (float)NROWS;

    float b1p = 1.0f, b2p = 1.0f;

    for (int step = 0; step < NSTEPS; ++step) {
        b1p *= B1;
        b2p *= B2;

        // Wave-uniform per-step scalars (bias corrections folded):
        //   upd = LR * (m/c1) / (sqrt(v/c2) + eps)
        //       = [LR*sqrt(c2)/c1] * m / (sqrt(v) + eps*sqrt(c2))
        const float c1    = 1.0f - b1p;
        const float c2    = 1.0f - b2p;
        const float sc2   = __builtin_amdgcn_sqrtf(c2);
        const float alpha = LR * sc2 * __builtin_amdgcn_rcpf(c1);
        const float nalpha = -alpha;
        const float epst  = EPSA * sc2;

        // z = sp . W  (wave-wide reduction) + b
        float dot = 0.0f;
        #pragma unroll
        for (int i = 0; i < EPL; ++i) dot = fmaf(sp[i], w[i], dot);
        #pragma unroll
        for (int off = 32; off >= 1; off >>= 1) dot += __shfl_xor(dot, off, 64);

        // Wave-uniform sigmoid + dL/dz (precise; once per step)
        const float z  = dot + bb;
        const float p  = 1.0f / (1.0f + expf(-z));
        const float gz = two_over_b * (p - tc) * (p * (1.0f - p));

        #pragma unroll
        for (int i = 0; i < EPL; ++i) {
            const float diff = sp[i] - s0[i];
            // sign(0) = 0, matching torch/jax sign semantics
            const float sg = (diff > 0.0f) ? inv_nl1
                           : ((diff < 0.0f) ? -inv_nl1 : 0.0f);
            const float g  = fmaf(gz, w[i], sg);

            m[i] = fmaf(B1, m[i], OMB1 * g);
            v[i] = fmaf(B2, v[i], (OMB2 * g) * g);

            const float den = __builtin_amdgcn_sqrtf(v[i]) + epst;
            const float r   = __builtin_amdgcn_rcpf(den);
            sp[i] = fmaf(nalpha, m[i] * r, sp[i]);
        }
    }

    float4* O4 = reinterpret_cast<float4*>(out + (size_t)row * DDIM);
    #pragma unroll
    for (int c = 0; c < 4; ++c) {
        float4 ov;
        ov.x = sp[c*4+0]; ov.y = sp[c*4+1]; ov.z = sp[c*4+2]; ov.w = sp[c*4+3];
        O4[c * 64 + lane] = ov;
    }
}

extern "C" void kernel_launch(void* const* d_in, const int* in_sizes, int n_in,
                              void* d_out, int out_size, void* d_ws, size_t ws_size,
                              hipStream_t stream) {
    const float* s     = (const float*)d_in[0];
    const float* tconf = (const float*)d_in[1];
    const float* W     = (const float*)d_in[2];
    const float* bias  = (const float*)d_in[3];
    float* out = (float*)d_out;

    dim3 grid(NROWS / WAVES_PER_BLOCK);  // 2048 blocks
    dim3 block(64 * WAVES_PER_BLOCK);    // 256 threads
    adam_rows_kernel<<<grid, block, 0, stream>>>(s, tconf, W, bias, out);
}

// Round 3
// 154.592 us; speedup vs baseline: 2.9967x; 1.2647x over previous
//
#include <hip/hip_runtime.h>
#include <math.h>

// Problem constants (match reference)
#define NROWS   8192
#define DDIM    1024
#define NSTEPS  50
#define EPL     16          // elements per lane: 1024 / 64
#define WAVES_PER_BLOCK 4   // 256 threads

// Adam hyperparams (double for host-side table computation)
#define LR_D   0.01
#define B1_D   0.9
#define B2_D   0.999
#define EPS_D  1e-8

struct StepTbl {
    float alpha[NSTEPS];   // LR*(1-B1)*sqrt((1-B2^t)/(1-B2))/(1-B1^t)
    float eps2[NSTEPS];    // EPS*sqrt((1-B2^t)/(1-B2))
};

__global__ __launch_bounds__(256) void adam_rows_kernel(
    const float* __restrict__ s,       // [NROWS, DDIM]
    const float* __restrict__ tconf,   // [NROWS, 1]
    const float* __restrict__ W,       // [1, DDIM]
    const float* __restrict__ bias,    // [1]
    float* __restrict__ out,           // [NROWS, DDIM]
    const StepTbl tbl)
{
    const int lane = threadIdx.x & 63;
    const int wave = threadIdx.x >> 6;
    const int row  = blockIdx.x * WAVES_PER_BLOCK + wave;

    const float bb = bias[0];
    const float tc = tconf[row];

    const float B1f = 0.9f;
    const float B2f = 0.999f;
    const float gz_scale = 2.0f / (float)NROWS;
    const float INV_NL1  = 1.1920929e-7f;   // 2^-23 == 1/(NROWS*DDIM) exactly
    const float SIGN_MUL = 3.4e38f;         // lifts any nonzero |diff| above 2^-23
    const float NLOG2E   = -1.44269504f;

    float w[EPL], s0[EPL], sp[EPL], M[EPL], V[EPL];

    const float4* W4 = reinterpret_cast<const float4*>(W);
    const float4* S4 = reinterpret_cast<const float4*>(s + (size_t)row * DDIM);

    float dot = 0.0f;   // sp . w, maintained across steps
    #pragma unroll
    for (int c = 0; c < 4; ++c) {
        float4 wv = W4[c * 64 + lane];
        float4 sv = S4[c * 64 + lane];
        w[c*4+0] = wv.x; w[c*4+1] = wv.y; w[c*4+2] = wv.z; w[c*4+3] = wv.w;
        s0[c*4+0] = sv.x; s0[c*4+1] = sv.y; s0[c*4+2] = sv.z; s0[c*4+3] = sv.w;
    }
    #pragma unroll
    for (int i = 0; i < EPL; ++i) {
        sp[i] = s0[i]; M[i] = 0.0f; V[i] = 0.0f;
        dot = fmaf(sp[i], w[i], dot);
    }

    for (int step = 0; step < NSTEPS; ++step) {
        // wave-wide reduce of dot
        #pragma unroll
        for (int off = 32; off >= 1; off >>= 1) dot += __shfl_xor(dot, off, 64);

        // wave-uniform sigmoid + dL/dz (fast trans ops; ~2 ulp)
        const float z  = dot + bb;
        const float e  = __builtin_amdgcn_exp2f(z * NLOG2E);       // e^-z
        const float p  = __builtin_amdgcn_rcpf(1.0f + e);
        const float gz = gz_scale * (p - tc) * (p * (1.0f - p));

        const float alpha = tbl.alpha[step];
        const float eps2  = tbl.eps2[step];

        dot = 0.0f;
        #pragma unroll
        for (int i = 0; i < EPL; ++i) {
            const float diff = sp[i] - s0[i];
            // sign(diff) * 2^-23, sign(0)=0 exactly
            const float sg = __builtin_amdgcn_fmed3f(diff * SIGN_MUL, -INV_NL1, INV_NL1);
            const float g  = fmaf(gz, w[i], sg);

            M[i] = fmaf(B1f, M[i], g);              // M = b1*M + g
            V[i] = fmaf(g, g, V[i] * B2f);          // V = b2*V + g^2

            const float r = __builtin_amdgcn_rcpf(__builtin_amdgcn_sqrtf(V[i]) + eps2);
            sp[i] = fmaf(-alpha, M[i] * r, sp[i]);

            dot = fmaf(sp[i], w[i], dot);           // next step's dot
        }
    }

    float4* O4 = reinterpret_cast<float4*>(out + (size_t)row * DDIM);
    #pragma unroll
    for (int c = 0; c < 4; ++c) {
        float4 ov;
        ov.x = sp[c*4+0]; ov.y = sp[c*4+1]; ov.z = sp[c*4+2]; ov.w = sp[c*4+3];
        O4[c * 64 + lane] = ov;
    }
}

extern "C" void kernel_launch(void* const* d_in, const int* in_sizes, int n_in,
                              void* d_out, int out_size, void* d_ws, size_t ws_size,
                              hipStream_t stream) {
    const float* s     = (const float*)d_in[0];
    const float* tconf = (const float*)d_in[1];
    const float* W     = (const float*)d_in[2];
    const float* bias  = (const float*)d_in[3];
    float* out = (float*)d_out;

    // Host-side per-step Adam constants (double precision, then narrowed).
    StepTbl tbl;
    double b1p = 1.0, b2p = 1.0;
    for (int t = 0; t < NSTEPS; ++t) {
        b1p *= B1_D;
        b2p *= B2_D;
        const double c1 = 1.0 - b1p;            // 1 - B1^t
        const double c2 = 1.0 - b2p;            // 1 - B2^t
        const double sc = sqrt(c2 / (1.0 - B2_D));   // sqrt((1-B2^t)/(1-B2))
        tbl.alpha[t] = (float)(LR_D * (1.0 - B1_D) * sc / c1);
        tbl.eps2[t]  = (float)(EPS_D * sc);
    }

    dim3 grid(NROWS / WAVES_PER_BLOCK);  // 2048 blocks
    dim3 block(64 * WAVES_PER_BLOCK);    // 256 threads
    adam_rows_kernel<<<grid, block, 0, stream>>>(s, tconf, W, bias, out, tbl);
}